// Round 4
// baseline (80.631 us; speedup 1.0000x reference)
//
#include <hip/hip_runtime.h>

// RotationalConv2D R6: 16x16-px blocks (256 total), no split-K, no reduce.
// Per block: stage 20x20x16 input + bf16 W (LDS) + per-px rotation params;
// each wave owns a 4-row strip (4 M-tiles x 1 row) and runs the FULL K=400
// loop (13 chunks of K=32 = 2 taps), building A-fragments in registers via
// blend8 (proven in R5) and reading B-fragments from LDS-staged bf16 W.
// Results final in-register -> direct store. 3 barriers total.

#define KS     5
#define TILE   16
#define TW     (TILE + KS - 1)     // 20
#define CPAD   20                  // padded channel stride (floats)
#define C_IN   16
#define F_OUT  32
#define H_IN   128
#define W_IN   128
#define HO     124
#define WO     124
#define NBATCH 4
#define EPSF   1e-7f
#define BLOCK  256
#define KW     400                 // K = 25*16
#define SWS    408                 // sW row stride in shorts (816 B)

// LDS layout (bytes):
//   s_in  [0,     32000)   20*20*CPAD*4
//   s_int [32000, 33680)   20*21*4
//   s_ang [33680, 37776)   256*16
//   sW    [37776, 63888)   32*408*2
#define SINT_OFF 32000
#define ANG_OFF  33680
#define SW_OFF   37776
#define SMEM_BYTES 63888

typedef __attribute__((ext_vector_type(8))) short  short8;   // 8 bf16
typedef __attribute__((ext_vector_type(4))) short  short4v;  // 4 bf16
typedef __attribute__((ext_vector_type(4))) float  floatx4;

static __device__ __forceinline__ short f2bf(float f) {
    union { float f; unsigned u; } v; v.f = f;
    unsigned r = v.u + 0x7fffu + ((v.u >> 16) & 1u);   // RNE
    return (short)(r >> 16);
}

// Blend 8 channels [ch0, ch0+8) of tap t for pixel (lxq, lyq) -> bf16 x8.
// (unchanged from R5 -- proven)
static __device__ __forceinline__ short8 blend8(
    const float* __restrict__ s_in, int lxq, int lyq,
    float co, float si, float xo, float yo, int t, int ch0)
{
    const float scl = 1.0f / (1.0f + EPSF);
    int ky = t / KS, kx = t - KS * ky;
    float sx = (co * (float)kx - si * (float)ky + xo) * scl;
    float sy = (si * (float)kx + co * (float)ky + yo) * scl;
    float fx0 = floorf(sx), fy0 = floorf(sy);
    float wx = sx - fx0, wy = sy - fy0;
    int x0 = (int)fx0, y0 = (int)fy0;
    int x1 = x0 + 1, y1 = y0 + 1;
    float vx0 = (x0 >= 0 && x0 < KS) ? 1.f : 0.f;
    float vx1 = (x1 >= 0 && x1 < KS) ? 1.f : 0.f;
    float vy0 = (y0 >= 0 && y0 < KS) ? 1.f : 0.f;
    float vy1 = (y1 >= 0 && y1 < KS) ? 1.f : 0.f;
    float w00 = (1.f - wx) * (1.f - wy) * vx0 * vy0;
    float w01 = wx * (1.f - wy) * vx1 * vy0;
    float w10 = (1.f - wx) * wy * vx0 * vy1;
    float w11 = wx * wy * vx1 * vy1;
    int cx0 = min(max(x0, 0), KS - 1), cx1 = min(max(x1, 0), KS - 1);
    int cy0 = min(max(y0, 0), KS - 1), cy1 = min(max(y1, 0), KS - 1);
    const float* p00 = &s_in[((lyq + cy0) * TW + (lxq + cx0)) * CPAD + ch0];
    const float* p01 = &s_in[((lyq + cy0) * TW + (lxq + cx1)) * CPAD + ch0];
    const float* p10 = &s_in[((lyq + cy1) * TW + (lxq + cx0)) * CPAD + ch0];
    const float* p11 = &s_in[((lyq + cy1) * TW + (lxq + cx1)) * CPAD + ch0];
    float r[8];
    #pragma unroll
    for (int cv = 0; cv < 2; ++cv) {
        float4 a = *(const float4*)(p00 + 4 * cv);
        float4 b = *(const float4*)(p01 + 4 * cv);
        float4 c = *(const float4*)(p10 + 4 * cv);
        float4 d = *(const float4*)(p11 + 4 * cv);
        r[4*cv+0] = w00 * a.x + w01 * b.x + w10 * c.x + w11 * d.x;
        r[4*cv+1] = w00 * a.y + w01 * b.y + w10 * c.y + w11 * d.y;
        r[4*cv+2] = w00 * a.z + w01 * b.z + w10 * c.z + w11 * d.z;
        r[4*cv+3] = w00 * a.w + w01 * b.w + w10 * c.w + w11 * d.w;
    }
    return (short8){f2bf(r[0]), f2bf(r[1]), f2bf(r[2]), f2bf(r[3]),
                    f2bf(r[4]), f2bf(r[5]), f2bf(r[6]), f2bf(r[7])};
}

__global__ __launch_bounds__(BLOCK, 2) void rotconv_kernel(
    const float* __restrict__ in, const float* __restrict__ Wg,
    const float* __restrict__ bg, float* __restrict__ out)
{
    __shared__ __align__(16) char smem[SMEM_BYTES];
    float*  s_in   = (float*)smem;
    float*  s_int  = (float*)(smem + SINT_OFF);
    float4* s_ang4 = (float4*)(smem + ANG_OFF);
    short*  sW     = (short*)(smem + SW_OFF);

    const int tid  = threadIdx.x;
    const int bx = blockIdx.x, by = blockIdx.y, bimg = blockIdx.z;
    const int ox = bx * TILE, oy = by * TILE;

    // ---- stage input tile (20x20x16) as float4 chunks ----
    const float* inb = in + (size_t)bimg * (H_IN * W_IN * C_IN);
    for (int i = tid; i < TW * TW * (C_IN / 4); i += BLOCK) {
        int cv = i & 3;
        int pp = i >> 2;
        int x = pp % TW, y = pp / TW;
        int gy = oy + y, gx = ox + x;
        float4 v = make_float4(0.f, 0.f, 0.f, 0.f);
        if (gy < H_IN && gx < W_IN)
            v = *(const float4*)(inb + ((size_t)(gy * W_IN + gx) * C_IN) + 4 * cv);
        *(float4*)(&s_in[pp * CPAD + 4 * cv]) = v;
    }

    // ---- stage W -> bf16 LDS (fragment-aligned, once per block) ----
    // sW[f][k], row stride SWS shorts. 3200 float4s.
    for (int i = tid; i < (F_OUT * KW) / 4; i += BLOCK) {
        int f = i / 100;            // 100 float4s per f row
        int k = (i - f * 100) * 4;
        float4 w = *(const float4*)(Wg + (size_t)f * KW + k);
        short4v h = {f2bf(w.x), f2bf(w.y), f2bf(w.z), f2bf(w.w)};
        *(short4v*)(&sW[f * SWS + k]) = h;
    }
    __syncthreads();

    // ---- intensity = channel sum (20x20) ----
    for (int pp = tid; pp < TW * TW; pp += BLOCK) {
        const float* sp = &s_in[pp * CPAD];
        float4 a = *(const float4*)(sp);
        float4 b = *(const float4*)(sp + 4);
        float4 c = *(const float4*)(sp + 8);
        float4 d = *(const float4*)(sp + 12);
        float s = ((a.x + a.y) + (a.z + a.w)) + ((b.x + b.y) + (b.z + b.w))
                + ((c.x + c.y) + (c.z + c.w)) + ((d.x + d.y) + (d.z + d.w));
        s_int[(pp / TW) * (TW + 1) + (pp % TW)] = s;
    }
    __syncthreads();

    // ---- per-pixel rotation params (all 256 threads, px = tid) ----
    {
        const int alx = tid & 15, aly = tid >> 4;
        float tot = EPSF, cr = 0.f, cc = 0.f;
        #pragma unroll
        for (int dy = 0; dy < KS; ++dy)
            #pragma unroll
            for (int dx = 0; dx < KS; ++dx) {
                float v = s_int[(aly + dy) * (TW + 1) + (alx + dx)];
                tot += v; cr += v * (float)dy; cc += v * (float)dx;
            }
        cr /= tot; cc /= tot;
        float ang = atan2f(cr - 2.0f, cc - 2.0f + EPSF);
        float si, co;
        sincosf(ang, &si, &co);
        float xoff = (4.0f - (co * 4.0f - si * 4.0f)) * 0.5f;
        float yoff = (4.0f - (si * 4.0f + co * 4.0f)) * 0.5f;
        s_ang4[tid] = make_float4(co, si, xoff, yoff);
    }
    __syncthreads();

    const int p    = tid & 63;     // lane
    const int wv   = tid >> 6;     // wave id 0..3 -> rows 4wv..4wv+3
    const int col  = p & 15;       // MFMA lane&15 (pixel-x AND f-within-Ntile)
    const int quad = p >> 4;       // MFMA lane>>4
    const int ch0  = (quad & 1) * 8;

    // per-m rotation params: pixel (row 4wv+m, x=col)
    float4 angs[4];
    #pragma unroll
    for (int m = 0; m < 4; ++m) angs[m] = s_ang4[(4 * wv + m) * 16 + col];

    floatx4 acc[4][2];
    {
        float bv0 = bg[col], bv1 = bg[col + 16];
        #pragma unroll
        for (int m = 0; m < 4; ++m) {
            acc[m][0] = (floatx4){bv0, bv0, bv0, bv0};
            acc[m][1] = (floatx4){bv1, bv1, bv1, bv1};
        }
    }

    const short8 zero8 = {0,0,0,0,0,0,0,0};

    // ---- full-K loop: 13 chunks of K=32 (2 taps). quad0/1 -> tap 2c, quad2/3 -> 2c+1
    for (int c = 0; c < 13; ++c) {
        const int tq = 2 * c + (quad >> 1);
        const bool val = (tq < KS * KS);       // false only for c=12, quads 2,3

        short8 bf0 = zero8, bf1 = zero8;
        if (val) {
            bf0 = *(const short8*)(&sW[col * SWS + tq * 16 + ch0]);
            bf1 = *(const short8*)(&sW[(col + 16) * SWS + tq * 16 + ch0]);
        }
        #pragma unroll
        for (int m = 0; m < 4; ++m) {
            short8 av = zero8;
            if (val)
                av = blend8(s_in, col, 4 * wv + m,
                            angs[m].x, angs[m].y, angs[m].z, angs[m].w,
                            tq, ch0);
            acc[m][0] = __builtin_amdgcn_mfma_f32_16x16x32_bf16(av, bf0, acc[m][0], 0, 0, 0);
            acc[m][1] = __builtin_amdgcn_mfma_f32_16x16x32_bf16(av, bf1, acc[m][1], 0, 0, 0);
        }
    }

    // ---- epilogue: D[pixel-x = 4*quad+r][f = col]; row = 4wv+m ----
    #pragma unroll
    for (int m = 0; m < 4; ++m) {
        const int ho = oy + 4 * wv + m;
        if (ho < HO) {
            #pragma unroll
            for (int r = 0; r < 4; ++r) {
                const int wo = ox + 4 * quad + r;
                if (wo < WO) {
                    float* op = out + (((size_t)bimg * HO + ho) * WO + wo) * F_OUT + col;
                    op[0]  = acc[m][0][r];
                    op[16] = acc[m][1][r];
                }
            }
        }
    }
}

extern "C" void kernel_launch(void* const* d_in, const int* in_sizes, int n_in,
                              void* d_out, int out_size, void* d_ws, size_t ws_size,
                              hipStream_t stream) {
    const float* in = (const float*)d_in[0];
    const float* Wg = (const float*)d_in[1];
    const float* bg = (const float*)d_in[2];
    float* out      = (float*)d_out;
    dim3 grid((WO + TILE - 1) / TILE, (HO + TILE - 1) / TILE, NBATCH);
    rotconv_kernel<<<grid, dim3(BLOCK), 0, stream>>>(in, Wg, bg, out);
}

// Round 6
// 73.591 us; speedup vs baseline: 1.0957x; 1.0957x over previous
//
#include <hip/hip_runtime.h>

// RotationalConv2D R8: R5 structure (1024 blocks, split-K across waves,
// register-direct A-fragments, zero K-loop barriers) + f16 blend/MFMA
// pipeline (R7), with the R7 bug fixed: intensity/centroid/angle are
// computed from the EXACT f32 staged tile (R5's proven path) -- the angle
// is ill-conditioned near centered centroids and cannot tolerate f16
// input rounding. A separate f16 copy of the tile feeds the blend loop:
//   - blend reads 4x ds_read_b128 (was 8x in R5)
//   - blend in packed f16 (v_pk_fma_f16), no f2bf chains
//   - mfma_f32_16x16x32_f16 (same fragment/D layout as bf16)
// 5 barriers total.

#define KS     5
#define TILE   8
#define TW     (TILE + KS - 1)     // 12
#define CPAD   20                  // f32 tile pixel stride (floats)
#define SINH   24                  // f16 tile pixel stride (halves, 48 B)
#define C_IN   16
#define F_OUT  32
#define H_IN   128
#define W_IN   128
#define HO     124
#define WO     124
#define NBATCH 4
#define EPSF   1e-7f
#define BLOCK  256
#define KW     400                 // K = 25*16

// LDS layout (bytes):
//   phase 1: s_in  [0,11520) f32 tile | s_int [11520,12144)
//            s_ang [12160,13184)     | s_inh [13184,20096) f16 tile
//   phase 2 (epilogue, after barrier): red [0,34816) -- aliases everything
#define SINT_OFF    11520
#define ANG_OFF     12160
#define SINH_OFF    13184
#define RED_STRIDE  34             // floats per pixel row (136 B)
#define RED_WAVE    (64 * RED_STRIDE)
#define SMEM_BYTES  34816

typedef _Float16 half8  __attribute__((ext_vector_type(8)));
typedef _Float16 half4v __attribute__((ext_vector_type(4)));
typedef __attribute__((ext_vector_type(4))) float floatx4;

// Blend 8 channels [ch0, ch0+8) of tap t for pixel (lxq, lyq) -> f16 x8.
// Weights computed in f32 (exact index math), blend in packed f16.
static __device__ __forceinline__ half8 blend8h(
    const _Float16* __restrict__ s_inh, int lxq, int lyq,
    float co, float si, float xo, float yo, int t, int ch0)
{
    const float scl = 1.0f / (1.0f + EPSF);
    int ky = t / KS, kx = t - KS * ky;
    float sx = (co * (float)kx - si * (float)ky + xo) * scl;
    float sy = (si * (float)kx + co * (float)ky + yo) * scl;
    float fx0 = floorf(sx), fy0 = floorf(sy);
    float wx = sx - fx0, wy = sy - fy0;
    int x0 = (int)fx0, y0 = (int)fy0;
    int x1 = x0 + 1, y1 = y0 + 1;
    float vx0 = (x0 >= 0 && x0 < KS) ? 1.f : 0.f;
    float vx1 = (x1 >= 0 && x1 < KS) ? 1.f : 0.f;
    float vy0 = (y0 >= 0 && y0 < KS) ? 1.f : 0.f;
    float vy1 = (y1 >= 0 && y1 < KS) ? 1.f : 0.f;
    float w00 = (1.f - wx) * (1.f - wy) * vx0 * vy0;
    float w01 = wx * (1.f - wy) * vx1 * vy0;
    float w10 = (1.f - wx) * wy * vx0 * vy1;
    float w11 = wx * wy * vx1 * vy1;
    int cx0 = min(max(x0, 0), KS - 1), cx1 = min(max(x1, 0), KS - 1);
    int cy0 = min(max(y0, 0), KS - 1), cy1 = min(max(y1, 0), KS - 1);
    const _Float16* p00 = &s_inh[((lyq + cy0) * TW + (lxq + cx0)) * SINH + ch0];
    const _Float16* p01 = &s_inh[((lyq + cy0) * TW + (lxq + cx1)) * SINH + ch0];
    const _Float16* p10 = &s_inh[((lyq + cy1) * TW + (lxq + cx0)) * SINH + ch0];
    const _Float16* p11 = &s_inh[((lyq + cy1) * TW + (lxq + cx1)) * SINH + ch0];
    half8 a = *(const half8*)p00;
    half8 b = *(const half8*)p01;
    half8 c = *(const half8*)p10;
    half8 d = *(const half8*)p11;
    _Float16 h00 = (_Float16)w00, h01 = (_Float16)w01;
    _Float16 h10 = (_Float16)w10, h11 = (_Float16)w11;
    half8 W00 = {h00,h00,h00,h00,h00,h00,h00,h00};
    half8 W01 = {h01,h01,h01,h01,h01,h01,h01,h01};
    half8 W10 = {h10,h10,h10,h10,h10,h10,h10,h10};
    half8 W11 = {h11,h11,h11,h11,h11,h11,h11,h11};
    return a * W00 + b * W01 + c * W10 + d * W11;
}

__global__ __launch_bounds__(BLOCK, 2) void rotconv_kernel(
    const float* __restrict__ in, const float* __restrict__ Wg,
    const float* __restrict__ bg, float* __restrict__ out)
{
    __shared__ __align__(16) char smem[SMEM_BYTES];
    float*    s_in   = (float*)smem;
    float*    s_int  = (float*)(smem + SINT_OFF);
    float4*   s_ang4 = (float4*)(smem + ANG_OFF);
    _Float16* s_inh  = (_Float16*)(smem + SINH_OFF);
    float*    red    = (float*)smem;           // epilogue alias

    const int tid  = threadIdx.x;
    const int bx = blockIdx.x, by = blockIdx.y, bimg = blockIdx.z;
    const int ox = bx * TILE, oy = by * TILE;

    // ---- stage input tile (12x12x16) as f32 (exact, for intensity/angle) ----
    const float* inb = in + (size_t)bimg * (H_IN * W_IN * C_IN);
    for (int i = tid; i < TW * TW * (C_IN / 4); i += BLOCK) {
        int cv = i & 3;
        int pp = i >> 2;
        int x = pp % TW, y = pp / TW;
        int gy = oy + y, gx = ox + x;
        float4 v = make_float4(0.f, 0.f, 0.f, 0.f);
        if (gy < H_IN && gx < W_IN)
            v = *(const float4*)(inb + ((size_t)(gy * W_IN + gx) * C_IN) + 4 * cv);
        *(float4*)(&s_in[pp * CPAD + 4 * cv]) = v;
    }
    __syncthreads();

    // ---- intensity = channel sum (f32, same order as R5 -- proven) ----
    for (int pp = tid; pp < TW * TW; pp += BLOCK) {
        const float* sp = &s_in[pp * CPAD];
        float s = 0.f;
        #pragma unroll
        for (int c = 0; c < C_IN; ++c) s += sp[c];
        s_int[(pp / TW) * (TW + 1) + (pp % TW)] = s;
    }
    __syncthreads();

    // ---- angle (threads 0..63, f32 exact) + f32->f16 tile conversion ----
    if (tid < 64) {
        const int alx = tid & 7, aly = tid >> 3;
        float tot = EPSF, cr = 0.f, cc = 0.f;
        #pragma unroll
        for (int dy = 0; dy < KS; ++dy)
            #pragma unroll
            for (int dx = 0; dx < KS; ++dx) {
                float v = s_int[(aly + dy) * (TW + 1) + (alx + dx)];
                tot += v; cr += v * (float)dy; cc += v * (float)dx;
            }
        cr /= tot; cc /= tot;
        float ang = atan2f(cr - 2.0f, cc - 2.0f + EPSF);
        float si, co;
        sincosf(ang, &si, &co);
        float xoff = (4.0f - (co * 4.0f - si * 4.0f)) * 0.5f;
        float yoff = (4.0f - (si * 4.0f + co * 4.0f)) * 0.5f;
        s_ang4[tid] = make_float4(co, si, xoff, yoff);
    }
    // conversion pass (all 256 threads; independent of angle computation)
    for (int i = tid; i < TW * TW * (C_IN / 4); i += BLOCK) {
        int cv = i & 3;
        int pp = i >> 2;
        float4 v = *(const float4*)(&s_in[pp * CPAD + 4 * cv]);
        half4v h = {(_Float16)v.x, (_Float16)v.y, (_Float16)v.z, (_Float16)v.w};
        *(half4v*)(&s_inh[pp * SINH + 4 * cv]) = h;
    }
    __syncthreads();

    const int p    = tid & 63;     // lane
    const int wv   = tid >> 6;     // wave id 0..3
    const int col  = p & 15;       // MFMA lane&15
    const int quad = p >> 4;       // MFMA lane>>4

    // hoist per-m rotation params (pixel 16m+col) into registers
    float4 angs[4];
    #pragma unroll
    for (int m = 0; m < 4; ++m) angs[m] = s_ang4[16 * m + col];

    // ---- split-K: wave wv owns taps {wv, wv+4, ...}; step s = (wv+8s, wv+8s+4)
    floatx4 acc[4][2];
    #pragma unroll
    for (int m = 0; m < 4; ++m) {
        acc[m][0] = (floatx4){0.f, 0.f, 0.f, 0.f};
        acc[m][1] = acc[m][0];
    }

    const int nstep = (wv == 0) ? 4 : 3;       // wave 0 also covers tap 24
    const int lxq = col & 7, lyq0 = col >> 3;  // pixel 16m+col coords (lyq = 2m+lyq0)
    const int ch0 = (quad & 1) * 8;            // this lane's channel half
    const half8 zero8 = {0,0,0,0,0,0,0,0};

    #pragma unroll
    for (int s = 0; s < 4; ++s) {
        if (s < nstep) {
            const int ta = wv + 8 * s;         // < 25 whenever executed
            const int tb = ta + 4;             // >= 25 only for (wv==0, s==3)
            const int tq = (quad < 2) ? ta : tb;

            // B-fragment: lane holds B[8*quad+j][col] = W[f][tq*16 + ch0 + j]
            half8 bf0 = zero8, bf1 = zero8;
            if (tq < KS * KS) {
                const float* wp0 = Wg + (size_t)col * KW + tq * 16 + ch0;
                float4 a = *(const float4*)(wp0);
                float4 b = *(const float4*)(wp0 + 4);
                bf0 = (half8){(_Float16)a.x, (_Float16)a.y, (_Float16)a.z, (_Float16)a.w,
                              (_Float16)b.x, (_Float16)b.y, (_Float16)b.z, (_Float16)b.w};
                const float* wp1 = wp0 + (size_t)16 * KW;
                float4 c = *(const float4*)(wp1);
                float4 d = *(const float4*)(wp1 + 4);
                bf1 = (half8){(_Float16)c.x, (_Float16)c.y, (_Float16)c.z, (_Float16)c.w,
                              (_Float16)d.x, (_Float16)d.y, (_Float16)d.z, (_Float16)d.w};
            }

            // A-fragments in registers: pixel 16m+col, tap tq, ch ch0..ch0+7
            #pragma unroll
            for (int m = 0; m < 4; ++m) {
                half8 av = zero8;
                if (tq < KS * KS)
                    av = blend8h(s_inh, lxq, 2 * m + lyq0,
                                 angs[m].x, angs[m].y, angs[m].z, angs[m].w,
                                 tq, ch0);
                acc[m][0] = __builtin_amdgcn_mfma_f32_16x16x32_f16(av, bf0, acc[m][0], 0, 0, 0);
                acc[m][1] = __builtin_amdgcn_mfma_f32_16x16x32_f16(av, bf1, acc[m][1], 0, 0, 0);
            }
        }
    }

    // ---- cross-wave reduce (2 barriers) ----
    __syncthreads();                           // all waves done reading s_in*/s_ang
    #pragma unroll
    for (int m = 0; m < 4; ++m)
        #pragma unroll
        for (int n = 0; n < 2; ++n)
            #pragma unroll
            for (int r = 0; r < 4; ++r) {
                int px = 16 * m + 4 * quad + r;          // D: row = quad*4+reg
                red[wv * RED_WAVE + px * RED_STRIDE + n * 16 + col] = acc[m][n][r];
            }
    __syncthreads();

    // thread tid -> pixel tid>>2, f block (tid&3)*8 ; sum 4 partials + bias
    const int rpx = tid >> 2;
    const int rf0 = (tid & 3) * 8;
    float sum[8];
    #pragma unroll
    for (int j = 0; j < 8; ++j) sum[j] = bg[rf0 + j];
    #pragma unroll
    for (int w = 0; w < 4; ++w) {
        const float* rp = red + w * RED_WAVE + rpx * RED_STRIDE + rf0;
        #pragma unroll
        for (int j = 0; j < 8; ++j) sum[j] += rp[j];
    }
    const int ho = oy + (rpx >> 3), wo = ox + (rpx & 7);
    if (ho < HO && wo < WO) {
        float* op = out + (((size_t)bimg * HO + ho) * WO + wo) * F_OUT + rf0;
        *(float4*)op       = make_float4(sum[0], sum[1], sum[2], sum[3]);
        *(float4*)(op + 4) = make_float4(sum[4], sum[5], sum[6], sum[7]);
    }
}

extern "C" void kernel_launch(void* const* d_in, const int* in_sizes, int n_in,
                              void* d_out, int out_size, void* d_ws, size_t ws_size,
                              hipStream_t stream) {
    const float* in = (const float*)d_in[0];
    const float* Wg = (const float*)d_in[1];
    const float* bg = (const float*)d_in[2];
    float* out      = (float*)d_out;
    dim3 grid((WO + TILE - 1) / TILE, (HO + TILE - 1) / TILE, NBATCH);
    rotconv_kernel<<<grid, dim3(BLOCK), 0, stream>>>(in, Wg, bg, out);
}

// Round 7
// 71.541 us; speedup vs baseline: 1.1271x; 1.0287x over previous
//
#include <hip/hip_runtime.h>

// RotationalConv2D R9: R8's proven f16 K-loop + collapsed prologue.
//  - stage writes f16 tile DIRECTLY + exact-f32 channel partials (no f32 tile,
//    no separate intensity pass, no conversion pass)
//  - angle from partials via one ds_read_b128/tap; cos/sin computed
//    algebraically (x/r, y/r) instead of atan2f+sincosf
//  - K-loop (split-K across waves, register-direct A-frags, zero barriers),
//    cross-wave reduce, epilogue: identical to R8 (proven).
// 4 barriers total.

#define KS     5
#define TILE   8
#define TW     (TILE + KS - 1)     // 12
#define SINH   24                  // f16 tile pixel stride (halves, 48 B)
#define C_IN   16
#define F_OUT  32
#define H_IN   128
#define W_IN   128
#define HO     124
#define WO     124
#define NBATCH 4
#define EPSF   1e-7f
#define BLOCK  256
#define KW     400                 // K = 25*16

// LDS layout (bytes):
//   phase 1: s_inh [0,6912) f16 tile | s_part [6912,9216) f32 partials
//            s_ang [9216,10240)
//   phase 2 (epilogue, after barrier): red [0,34816) -- aliases everything
#define PART_OFF    6912
#define ANG_OFF     9216
#define RED_STRIDE  34             // floats per pixel row (136 B)
#define RED_WAVE    (64 * RED_STRIDE)
#define SMEM_BYTES  34816

typedef _Float16 half8  __attribute__((ext_vector_type(8)));
typedef _Float16 half4v __attribute__((ext_vector_type(4)));
typedef __attribute__((ext_vector_type(4))) float floatx4;

// Blend 8 channels [ch0, ch0+8) of tap t for pixel (lxq, lyq) -> f16 x8.
// Weights computed in f32 (exact index math), blend in packed f16. (R8-proven)
static __device__ __forceinline__ half8 blend8h(
    const _Float16* __restrict__ s_inh, int lxq, int lyq,
    float co, float si, float xo, float yo, int t, int ch0)
{
    const float scl = 1.0f / (1.0f + EPSF);
    int ky = t / KS, kx = t - KS * ky;
    float sx = (co * (float)kx - si * (float)ky + xo) * scl;
    float sy = (si * (float)kx + co * (float)ky + yo) * scl;
    float fx0 = floorf(sx), fy0 = floorf(sy);
    float wx = sx - fx0, wy = sy - fy0;
    int x0 = (int)fx0, y0 = (int)fy0;
    int x1 = x0 + 1, y1 = y0 + 1;
    float vx0 = (x0 >= 0 && x0 < KS) ? 1.f : 0.f;
    float vx1 = (x1 >= 0 && x1 < KS) ? 1.f : 0.f;
    float vy0 = (y0 >= 0 && y0 < KS) ? 1.f : 0.f;
    float vy1 = (y1 >= 0 && y1 < KS) ? 1.f : 0.f;
    float w00 = (1.f - wx) * (1.f - wy) * vx0 * vy0;
    float w01 = wx * (1.f - wy) * vx1 * vy0;
    float w10 = (1.f - wx) * wy * vx0 * vy1;
    float w11 = wx * wy * vx1 * vy1;
    int cx0 = min(max(x0, 0), KS - 1), cx1 = min(max(x1, 0), KS - 1);
    int cy0 = min(max(y0, 0), KS - 1), cy1 = min(max(y1, 0), KS - 1);
    const _Float16* p00 = &s_inh[((lyq + cy0) * TW + (lxq + cx0)) * SINH + ch0];
    const _Float16* p01 = &s_inh[((lyq + cy0) * TW + (lxq + cx1)) * SINH + ch0];
    const _Float16* p10 = &s_inh[((lyq + cy1) * TW + (lxq + cx0)) * SINH + ch0];
    const _Float16* p11 = &s_inh[((lyq + cy1) * TW + (lxq + cx1)) * SINH + ch0];
    half8 a = *(const half8*)p00;
    half8 b = *(const half8*)p01;
    half8 c = *(const half8*)p10;
    half8 d = *(const half8*)p11;
    _Float16 h00 = (_Float16)w00, h01 = (_Float16)w01;
    _Float16 h10 = (_Float16)w10, h11 = (_Float16)w11;
    half8 W00 = {h00,h00,h00,h00,h00,h00,h00,h00};
    half8 W01 = {h01,h01,h01,h01,h01,h01,h01,h01};
    half8 W10 = {h10,h10,h10,h10,h10,h10,h10,h10};
    half8 W11 = {h11,h11,h11,h11,h11,h11,h11,h11};
    return a * W00 + b * W01 + c * W10 + d * W11;
}

__global__ __launch_bounds__(BLOCK, 2) void rotconv_kernel(
    const float* __restrict__ in, const float* __restrict__ Wg,
    const float* __restrict__ bg, float* __restrict__ out)
{
    __shared__ __align__(16) char smem[SMEM_BYTES];
    _Float16* s_inh  = (_Float16*)smem;
    float*    s_part = (float*)(smem + PART_OFF);
    float4*   s_ang4 = (float4*)(smem + ANG_OFF);
    float*    red    = (float*)smem;           // epilogue alias

    const int tid  = threadIdx.x;
    const int bx = blockIdx.x, by = blockIdx.y, bimg = blockIdx.z;
    const int ox = bx * TILE, oy = by * TILE;

    // ---- stage: f16 tile + exact-f32 channel partials, one pass ----
    const float* inb = in + (size_t)bimg * (H_IN * W_IN * C_IN);
    for (int i = tid; i < TW * TW * (C_IN / 4); i += BLOCK) {
        int cv = i & 3;
        int pp = i >> 2;
        int x = pp % TW, y = pp / TW;
        int gy = oy + y, gx = ox + x;
        float4 v = make_float4(0.f, 0.f, 0.f, 0.f);
        if (gy < H_IN && gx < W_IN)
            v = *(const float4*)(inb + ((size_t)(gy * W_IN + gx) * C_IN) + 4 * cv);
        half4v h = {(_Float16)v.x, (_Float16)v.y, (_Float16)v.z, (_Float16)v.w};
        *(half4v*)(&s_inh[pp * SINH + 4 * cv]) = h;
        s_part[pp * 4 + cv] = (v.x + v.y) + (v.z + v.w);
    }
    __syncthreads();

    // ---- angle (threads 0..63): intensity window from f32 partials ----
    if (tid < 64) {
        const int alx = tid & 7, aly = tid >> 3;
        float tot = EPSF, cr = 0.f, cc = 0.f;
        #pragma unroll
        for (int dy = 0; dy < KS; ++dy)
            #pragma unroll
            for (int dx = 0; dx < KS; ++dx) {
                float4 pv = *(const float4*)(&s_part[((aly + dy) * TW + (alx + dx)) * 4]);
                float v = (pv.x + pv.y) + (pv.z + pv.w);
                tot += v; cr += v * (float)dy; cc += v * (float)dx;
            }
        cr /= tot; cc /= tot;
        // cos/sin of atan2(dyv,dxv) computed algebraically
        float dyv = cr - 2.0f, dxv = cc - 2.0f + EPSF;
        float r = sqrtf(dxv * dxv + dyv * dyv);
        float co, si;
        if (r < 1e-20f) { co = 1.f; si = 0.f; }     // atan2(0,+0) = 0
        else           { float ri = 1.0f / r; co = dxv * ri; si = dyv * ri; }
        float xoff = (4.0f - (co * 4.0f - si * 4.0f)) * 0.5f;
        float yoff = (4.0f - (si * 4.0f + co * 4.0f)) * 0.5f;
        s_ang4[tid] = make_float4(co, si, xoff, yoff);
    }
    __syncthreads();

    const int p    = tid & 63;     // lane
    const int wv   = tid >> 6;     // wave id 0..3
    const int col  = p & 15;       // MFMA lane&15
    const int quad = p >> 4;       // MFMA lane>>4

    // hoist per-m rotation params (pixel 16m+col) into registers
    float4 angs[4];
    #pragma unroll
    for (int m = 0; m < 4; ++m) angs[m] = s_ang4[16 * m + col];

    // ---- split-K: wave wv owns taps {wv, wv+4, ...}; step s = (wv+8s, wv+8s+4)
    floatx4 acc[4][2];
    #pragma unroll
    for (int m = 0; m < 4; ++m) {
        acc[m][0] = (floatx4){0.f, 0.f, 0.f, 0.f};
        acc[m][1] = acc[m][0];
    }

    const int nstep = (wv == 0) ? 4 : 3;       // wave 0 also covers tap 24
    const int lxq = col & 7, lyq0 = col >> 3;  // pixel 16m+col coords (lyq = 2m+lyq0)
    const int ch0 = (quad & 1) * 8;            // this lane's channel half
    const half8 zero8 = {0,0,0,0,0,0,0,0};

    #pragma unroll
    for (int s = 0; s < 4; ++s) {
        if (s < nstep) {
            const int ta = wv + 8 * s;         // < 25 whenever executed
            const int tb = ta + 4;             // >= 25 only for (wv==0, s==3)
            const int tq = (quad < 2) ? ta : tb;

            // B-fragment: lane holds B[8*quad+j][col] = W[f][tq*16 + ch0 + j]
            half8 bf0 = zero8, bf1 = zero8;
            if (tq < KS * KS) {
                const float* wp0 = Wg + (size_t)col * KW + tq * 16 + ch0;
                float4 a = *(const float4*)(wp0);
                float4 b = *(const float4*)(wp0 + 4);
                bf0 = (half8){(_Float16)a.x, (_Float16)a.y, (_Float16)a.z, (_Float16)a.w,
                              (_Float16)b.x, (_Float16)b.y, (_Float16)b.z, (_Float16)b.w};
                const float* wp1 = wp0 + (size_t)16 * KW;
                float4 c = *(const float4*)(wp1);
                float4 d = *(const float4*)(wp1 + 4);
                bf1 = (half8){(_Float16)c.x, (_Float16)c.y, (_Float16)c.z, (_Float16)c.w,
                              (_Float16)d.x, (_Float16)d.y, (_Float16)d.z, (_Float16)d.w};
            }

            // A-fragments in registers: pixel 16m+col, tap tq, ch ch0..ch0+7
            #pragma unroll
            for (int m = 0; m < 4; ++m) {
                half8 av = zero8;
                if (tq < KS * KS)
                    av = blend8h(s_inh, lxq, 2 * m + lyq0,
                                 angs[m].x, angs[m].y, angs[m].z, angs[m].w,
                                 tq, ch0);
                acc[m][0] = __builtin_amdgcn_mfma_f32_16x16x32_f16(av, bf0, acc[m][0], 0, 0, 0);
                acc[m][1] = __builtin_amdgcn_mfma_f32_16x16x32_f16(av, bf1, acc[m][1], 0, 0, 0);
            }
        }
    }

    // ---- cross-wave reduce (2 barriers) ----
    __syncthreads();                           // all waves done reading s_inh/s_ang
    #pragma unroll
    for (int m = 0; m < 4; ++m)
        #pragma unroll
        for (int n = 0; n < 2; ++n)
            #pragma unroll
            for (int r = 0; r < 4; ++r) {
                int px = 16 * m + 4 * quad + r;          // D: row = quad*4+reg
                red[wv * RED_WAVE + px * RED_STRIDE + n * 16 + col] = acc[m][n][r];
            }
    __syncthreads();

    // thread tid -> pixel tid>>2, f block (tid&3)*8 ; sum 4 partials + bias
    const int rpx = tid >> 2;
    const int rf0 = (tid & 3) * 8;
    float sum[8];
    #pragma unroll
    for (int j = 0; j < 8; ++j) sum[j] = bg[rf0 + j];
    #pragma unroll
    for (int w = 0; w < 4; ++w) {
        const float* rp = red + w * RED_WAVE + rpx * RED_STRIDE + rf0;
        #pragma unroll
        for (int j = 0; j < 8; ++j) sum[j] += rp[j];
    }
    const int ho = oy + (rpx >> 3), wo = ox + (rpx & 7);
    if (ho < HO && wo < WO) {
        float* op = out + (((size_t)bimg * HO + ho) * WO + wo) * F_OUT + rf0;
        *(float4*)op       = make_float4(sum[0], sum[1], sum[2], sum[3]);
        *(float4*)(op + 4) = make_float4(sum[4], sum[5], sum[6], sum[7]);
    }
}

extern "C" void kernel_launch(void* const* d_in, const int* in_sizes, int n_in,
                              void* d_out, int out_size, void* d_ws, size_t ws_size,
                              hipStream_t stream) {
    const float* in = (const float*)d_in[0];
    const float* Wg = (const float*)d_in[1];
    const float* bg = (const float*)d_in[2];
    float* out      = (float*)d_out;
    dim3 grid((WO + TILE - 1) / TILE, (HO + TILE - 1) / TILE, NBATCH);
    rotconv_kernel<<<grid, dim3(BLOCK), 0, stream>>>(in, Wg, bg, out);
}